// Round 8
// baseline (5150.345 us; speedup 1.0000x reference)
//
#include <hip/hip_runtime.h>

#define T_LEN 16384
#define CIN   64
#define COUT  64
#define KTAPS 127
#define TN    512          // t-tile per block
#define XROWS 640          // staged x rows
#define WT_KS 4096         // COUT*CIN halfwords per tap slice

typedef __attribute__((ext_vector_type(8)))  __bf16 bf16x8;
typedef __attribute__((ext_vector_type(16))) float  f32x16;
typedef __attribute__((ext_vector_type(4)))  float  float4v;

__device__ inline unsigned short f2bf(float f) {
    unsigned u = __builtin_bit_cast(unsigned, f);
    u += 0x7fffu + ((u >> 16) & 1u);        // round-to-nearest-even
    return (unsigned short)(u >> 16);
}

// Wt[kp] slice (8KB) in MFMA-fragment order: each lane's A-fragment is one
// contiguous 16B chunk. Chunk c (0..511) of slice kp holds, for
// f=c>>6 (=cc*2+m), kg=(c>>5)&1, l31=c&31:
//   e=0..7:  bf16(W[m*32+l31][cc*16+kg*8+e][126-kp])
__global__ void wt_transform(const float* __restrict__ W,
                             unsigned short* __restrict__ Wt) {
    int t  = blockIdx.x * 256 + threadIdx.x;    // 127*512 threads
    int kp = t >> 9, c = t & 511;
    int f = c >> 6, kg = (c >> 5) & 1, l31 = c & 31;
    int cc = f >> 1, m = f & 1;
    int o = m * 32 + l31, ib = cc * 16 + kg * 8;
    const float* src = W + (o * CIN + ib) * KTAPS + (126 - kp);
    unsigned short tmp[8];
    #pragma unroll
    for (int e = 0; e < 8; ++e)
        tmp[e] = f2bf(src[e * KTAPS]);
    uint4 pk;
    pk.x = (unsigned)tmp[0] | ((unsigned)tmp[1] << 16);
    pk.y = (unsigned)tmp[2] | ((unsigned)tmp[3] << 16);
    pk.z = (unsigned)tmp[4] | ((unsigned)tmp[5] << 16);
    pk.w = (unsigned)tmp[6] | ((unsigned)tmp[7] << 16);
    *(uint4*)(Wt + kp * WT_KS + c * 8) = pk;
}

__global__ __launch_bounds__(1024, 4)
void conv_mfma(const float* __restrict__ x,
               const unsigned short* __restrict__ Wt,
               float* __restrict__ y) {
    // pool: xs [0,80K)  (merge scratch reuses [0,64K) at the end)
    __shared__ __align__(16) char pool[81920];
    unsigned short* xs = (unsigned short*)pool;   // [XROWS][64] swizzled

    const int tid = threadIdx.x;          // 0..1023
    const int bb  = blockIdx.x >> 5;      // batch
    const int tt  = blockIdx.x & 31;      // t-tile
    const int t0  = tt * TN;

    // ---- stage x window [t0-64, t0+576) transposed, 16-slot 8B swizzle:
    //      row w, cin c stored at w*64 + ((c>>2 ^ (w&15))<<2) + (c&3)
    {
        const int cin = tid >> 4;             // 0..63
        const int s   = tid & 15;
        const float* xrow = x + (bb * CIN + cin) * T_LEN;
        const int p = cin >> 2, c3 = cin & 3;
        for (int j = 0; j < 10; ++j) {
            const int w = 64 * j + 4 * s;
            const int u = t0 - 64 + w;        // global t (16B aligned)
            float4v v;
            if (u >= 0 && u + 4 <= T_LEN) {
                v = *(const float4v*)(xrow + u);
            } else {
                v.x = (u + 0 >= 0 && u + 0 < T_LEN) ? xrow[u + 0] : 0.f;
                v.y = (u + 1 >= 0 && u + 1 < T_LEN) ? xrow[u + 1] : 0.f;
                v.z = (u + 2 >= 0 && u + 2 < T_LEN) ? xrow[u + 2] : 0.f;
                v.w = (u + 3 >= 0 && u + 3 < T_LEN) ? xrow[u + 3] : 0.f;
            }
            #pragma unroll
            for (int e = 0; e < 4; ++e) {
                const int we = w + e;
                const float fv = (e == 0) ? v.x : (e == 1) ? v.y : (e == 2) ? v.z : v.w;
                xs[we * 64 + ((p ^ (we & 15)) << 2) + c3] = f2bf(fv);
            }
        }
    }

    const int lane   = tid & 63;
    const int wv     = tid >> 6;          // 0..15
    const int quad   = wv >> 2;           // tap-quarter owner (0..3)
    const int ww     = wv & 3;            // wave-in-quad: t-range
    const int l31    = lane & 31;
    const int kg     = lane >> 5;
    const int twbase = ww * 128;          // wave's 128-t range
    const int brow0  = twbase + l31 + 1;  // xs row at k'=0

    const int kp0  = quad * 32;
    const int ntap = (quad == 3) ? 31 : 32;

    // per-lane A-fragment global base: + kp*8192 + f*1024, f = cc*2+m
    const char* ab = (const char*)Wt + lane * 16;

    f32x16 acc[2][4] = {};                // [m: o-tile][n: t-tile]
    uint4 a0r[8], a1r[8];                 // ping-pong A prefetch (cross-tap)
    uint2 bAlo[4], bAhi[4];               // B reg double-buffer (cross-cc)
    uint2 bBlo[4], bBhi[4];

    #define LOADA(dst, kp)                                                  \
        do { const char* p_ = ab + (kp) * 8192;                             \
            _Pragma("unroll")                                               \
            for (int f = 0; f < 8; ++f)                                     \
                dst[f] = *(const uint4*)(p_ + f * 1024); } while (0)

    // issue 8 ds_read_b64 for (row rb, cin-chunk cidx) into lo/hi
    #define LOADB(lo, hi, rb, cidx)                                         \
        do { const int rb15_ = (rb) & 15;                                   \
            const char* xp_ = (const char*)xs + (rb) * 128;                 \
            const int q0_ = (((4 * (cidx) + 2 * kg + 0) ^ rb15_) << 3);     \
            const int q1_ = (((4 * (cidx) + 2 * kg + 1) ^ rb15_) << 3);     \
            _Pragma("unroll")                                               \
            for (int n = 0; n < 4; ++n) {                                   \
                lo[n] = *(const uint2*)(xp_ + n * 4096 + q0_);              \
                hi[n] = *(const uint2*)(xp_ + n * 4096 + q1_);              \
            } } while (0)

    #define MFMAB(lo, hi, ar, cidx)                                         \
        do { bf16x8 a0 = __builtin_bit_cast(bf16x8, ar[(cidx) * 2 + 0]);    \
            bf16x8 a1 = __builtin_bit_cast(bf16x8, ar[(cidx) * 2 + 1]);     \
            __builtin_amdgcn_s_setprio(1);                                  \
            _Pragma("unroll")                                               \
            for (int n = 0; n < 4; ++n) {                                   \
                uint4 t4 = {lo[n].x, lo[n].y, hi[n].x, hi[n].y};            \
                bf16x8 b = __builtin_bit_cast(bf16x8, t4);                  \
                acc[0][n] = __builtin_amdgcn_mfma_f32_32x32x16_bf16(a0, b, acc[0][n], 0, 0, 0); \
                acc[1][n] = __builtin_amdgcn_mfma_f32_32x32x16_bf16(a1, b, acc[1][n], 0, 0, 0); \
            }                                                               \
            __builtin_amdgcn_s_setprio(0); } while (0)

    // one tap, B-pipelined; do-while(0) so `if (...) TAP(...)` guards all.
    #define TAP(ar, kp)                                                     \
        do {                                                                \
            LOADB(bBlo, bBhi, brow0 + (kp), 1);  MFMAB(bAlo, bAhi, ar, 0);  \
            LOADB(bAlo, bAhi, brow0 + (kp), 2);  MFMAB(bBlo, bBhi, ar, 1);  \
            LOADB(bBlo, bBhi, brow0 + (kp), 3);  MFMAB(bAlo, bAhi, ar, 2);  \
            LOADB(bAlo, bAhi, brow0 + (kp) + 1, 0); MFMAB(bBlo, bBhi, ar, 3); \
        } while (0)

    LOADA(a0r, kp0);                       // overlaps the barrier
    __syncthreads();                       // xs ready
    LOADB(bAlo, bAhi, brow0 + kp0, 0);     // prime B pipeline

    // barrier-free main loop: waves drift freely over their tap ranges
    for (int i = 0; i < ntap; i += 2) {
        if (i + 1 < ntap) LOADA(a1r, kp0 + i + 1);    // A issue-early
        TAP(a0r, kp0 + i);
        if (i + 2 < ntap) LOADA(a0r, kp0 + i + 2);
        if (i + 1 < ntap) TAP(a1r, kp0 + i + 1);
    }

    // ---- merge: m=0 -> quad0, m=1 -> quad1 (xs dead now)
    __syncthreads();
    float* msm = (float*)pool;            // 64KB plane: (n*16+r) x 256 f32
    #pragma unroll
    for (int m = 0; m < 2; ++m) {
        const int own = m;                // owner quad for this m
        #pragma unroll
        for (int src = 0; src < 4; ++src) {
            if (src == own) continue;
            if (quad == src) {
                #pragma unroll
                for (int n = 0; n < 4; ++n)
                    #pragma unroll
                    for (int r = 0; r < 16; ++r)
                        msm[(n * 16 + r) * 256 + ww * 64 + lane] = acc[m][n][r];
            }
            __syncthreads();
            if (quad == own) {
                #pragma unroll
                for (int n = 0; n < 4; ++n)
                    #pragma unroll
                    for (int r = 0; r < 16; ++r)
                        acc[m][n][r] += msm[(n * 16 + r) * 256 + ww * 64 + lane];
            }
            __syncthreads();
        }
    }

    // ---- epilogue: quad m writes o-half m.  D col=l31 -> t,
    //      row = (r&3)+8*(r>>2)+4*kg -> o
    if (quad < 2) {
        const int m = quad;
        const int ybase = (bb * COUT) * T_LEN;
        #pragma unroll
        for (int n = 0; n < 4; ++n) {
            const int t = t0 + twbase + n * 32 + l31;
            #pragma unroll
            for (int r = 0; r < 16; ++r) {
                const int o = m * 32 + (r & 3) + 8 * (r >> 2) + 4 * kg;
                y[ybase + o * T_LEN + t] = acc[m][n][r];
            }
        }
    }
}

extern "C" void kernel_launch(void* const* d_in, const int* in_sizes, int n_in,
                              void* d_out, int out_size, void* d_ws, size_t ws_size,
                              hipStream_t stream) {
    const float* x = (const float*)d_in[0];
    const float* W = (const float*)d_in[1];
    float* yout = (float*)d_out;
    unsigned short* Wt = (unsigned short*)d_ws;   // 127*4096*2 B ~= 1 MB

    wt_transform<<<(KTAPS * 512) / 256, 256, 0, stream>>>(W, Wt);

    const int grid = 8 * (T_LEN / TN);            // 256 blocks, 1/CU
    conv_mfma<<<grid, 1024, 0, stream>>>(x, Wt, yout);
}

// Round 9
// 118.205 us; speedup vs baseline: 43.5712x; 43.5712x over previous
//
#include <hip/hip_runtime.h>

#define T_LEN 16384
#define CIN   64
#define COUT  64
#define KTAPS 127
#define TN    512          // t-tile per block
#define XROWS 640          // staged x rows
#define XPITCH_B 144       // row pitch in bytes (128 data + 16 pad)
#define WT_KS 4096         // COUT*CIN halfwords per tap slice

typedef __attribute__((ext_vector_type(8)))  __bf16 bf16x8;
typedef __attribute__((ext_vector_type(16))) float  f32x16;
typedef __attribute__((ext_vector_type(4)))  float  float4v;

__device__ inline unsigned short f2bf(float f) {
    unsigned u = __builtin_bit_cast(unsigned, f);
    u += 0x7fffu + ((u >> 16) & 1u);        // round-to-nearest-even
    return (unsigned short)(u >> 16);
}

// Wt[kp] slice (8KB) in MFMA-fragment order: each lane's A-fragment is one
// contiguous 16B chunk. Chunk c (0..511) of slice kp holds, for
// f=c>>6 (=cc*2+m), kg=(c>>5)&1, l31=c&31:
//   e=0..7:  bf16(W[m*32+l31][cc*16+kg*8+e][126-kp])
__global__ void wt_transform(const float* __restrict__ W,
                             unsigned short* __restrict__ Wt) {
    int t  = blockIdx.x * 256 + threadIdx.x;    // 127*512 threads
    int kp = t >> 9, c = t & 511;
    int f = c >> 6, kg = (c >> 5) & 1, l31 = c & 31;
    int cc = f >> 1, m = f & 1;
    int o = m * 32 + l31, ib = cc * 16 + kg * 8;
    const float* src = W + (o * CIN + ib) * KTAPS + (126 - kp);
    unsigned short tmp[8];
    #pragma unroll
    for (int e = 0; e < 8; ++e)
        tmp[e] = f2bf(src[e * KTAPS]);
    uint4 pk;
    pk.x = (unsigned)tmp[0] | ((unsigned)tmp[1] << 16);
    pk.y = (unsigned)tmp[2] | ((unsigned)tmp[3] << 16);
    pk.z = (unsigned)tmp[4] | ((unsigned)tmp[5] << 16);
    pk.w = (unsigned)tmp[6] | ((unsigned)tmp[7] << 16);
    *(uint4*)(Wt + kp * WT_KS + c * 8) = pk;
}

__global__ __launch_bounds__(512, 2)
void conv_mfma(const float* __restrict__ x,
               const unsigned short* __restrict__ Wt,
               float* __restrict__ y) {
    // pool: xs [0, 640*144=92160)  (merge scratch reuses [0,64K) at the end)
    __shared__ __align__(16) char pool[XROWS * XPITCH_B];
    unsigned short* xs = (unsigned short*)pool;   // [XROWS][72], 72hw=144B pitch

    const int tid = threadIdx.x;
    const int bb  = blockIdx.x >> 5;      // batch
    const int tt  = blockIdx.x & 31;      // t-tile
    const int t0  = tt * TN;

    // ---- stage x window [t0-64, t0+576) transposed into padded rows:
    //      row w, cin c at halfword w*72 + c  (pad breaks pow2 stride -> the
    //      per-lane 16B B-fragment read is bank-uniform, 8 words/bank floor)
    {
        const int cin = tid >> 3;             // 0..63
        const int s   = tid & 7;
        const float* xrow = x + (bb * CIN + cin) * T_LEN;
        for (int j = 0; j < 20; ++j) {
            const int w = 32 * j + 4 * s;
            const int u = t0 - 64 + w;        // global t (16B aligned)
            float4v v;
            if (u >= 0 && u + 4 <= T_LEN) {
                v = *(const float4v*)(xrow + u);
            } else {
                v.x = (u + 0 >= 0 && u + 0 < T_LEN) ? xrow[u + 0] : 0.f;
                v.y = (u + 1 >= 0 && u + 1 < T_LEN) ? xrow[u + 1] : 0.f;
                v.z = (u + 2 >= 0 && u + 2 < T_LEN) ? xrow[u + 2] : 0.f;
                v.w = (u + 3 >= 0 && u + 3 < T_LEN) ? xrow[u + 3] : 0.f;
            }
            #pragma unroll
            for (int e = 0; e < 4; ++e) {
                const int we = w + e;
                const float fv = (e == 0) ? v.x : (e == 1) ? v.y : (e == 2) ? v.z : v.w;
                xs[we * 72 + cin] = f2bf(fv);
            }
        }
    }

    const int lane   = tid & 63;
    const int wv     = tid >> 6;          // 0..7
    const int quad   = wv >> 2;           // tap-half owner (0/1)
    const int ww     = wv & 3;            // wave-in-quad: t-range
    const int l31    = lane & 31;
    const int kg     = lane >> 5;
    const int twbase = ww * 128;          // wave's 128-t range
    const int brow0  = twbase + l31 + 1;  // xs row at k'=0

    const int kp0  = quad ? 64 : 0;
    const int ntap = quad ? 63 : 64;

    // per-lane A-fragment global base: + kp*8192 + f*1024, f = cc*2+m
    const char* ab = (const char*)Wt + lane * 16;

    f32x16 acc[2][4] = {};                // [m: o-tile][n: t-tile]
    uint4 a0r[8], a1r[8];                 // ping-pong A prefetch (cross-tap)
    uint4 bA[4], bB[4];                   // B reg double-buffer (cross-cc)

    #define LOADA(dst, kp)                                                  \
        do { const char* p_ = ab + (kp) * 8192;                             \
            _Pragma("unroll")                                               \
            for (int f = 0; f < 8; ++f)                                     \
                dst[f] = *(const uint4*)(p_ + f * 1024); } while (0)

    // one ds_read_b128 per n: lane's B fragment is contiguous 16B
    #define LOADB(dst, rb, cidx)                                            \
        do { const char* xp_ = (const char*)xs + (rb) * XPITCH_B            \
                               + ((2 * (cidx) + kg) << 4);                  \
            _Pragma("unroll")                                               \
            for (int n = 0; n < 4; ++n)                                     \
                dst[n] = *(const uint4*)(xp_ + n * (32 * XPITCH_B));        \
        } while (0)

    #define MFMAB(bv, ar, cidx)                                             \
        do { bf16x8 a0 = __builtin_bit_cast(bf16x8, ar[(cidx) * 2 + 0]);    \
            bf16x8 a1 = __builtin_bit_cast(bf16x8, ar[(cidx) * 2 + 1]);     \
            __builtin_amdgcn_s_setprio(1);                                  \
            _Pragma("unroll")                                               \
            for (int n = 0; n < 4; ++n) {                                   \
                bf16x8 b = __builtin_bit_cast(bf16x8, bv[n]);               \
                acc[0][n] = __builtin_amdgcn_mfma_f32_32x32x16_bf16(a0, b, acc[0][n], 0, 0, 0); \
                acc[1][n] = __builtin_amdgcn_mfma_f32_32x32x16_bf16(a1, b, acc[1][n], 0, 0, 0); \
            }                                                               \
            __builtin_amdgcn_s_setprio(0); } while (0)

    // one tap, B-pipelined; do-while(0) so `if (...) TAP(...)` guards all.
    #define TAP(ar, kp)                                                     \
        do {                                                                \
            LOADB(bB, brow0 + (kp), 1);     MFMAB(bA, ar, 0);               \
            LOADB(bA, brow0 + (kp), 2);     MFMAB(bB, ar, 1);               \
            LOADB(bB, brow0 + (kp), 3);     MFMAB(bA, ar, 2);               \
            LOADB(bA, brow0 + (kp) + 1, 0); MFMAB(bB, ar, 3);               \
        } while (0)

    LOADA(a0r, kp0);                       // overlaps the barrier
    __syncthreads();                       // xs ready (only barrier pre-merge)
    LOADB(bA, brow0 + kp0, 0);             // prime B pipeline

    // barrier-free main loop: waves drift freely over their tap ranges
    for (int i = 0; i < ntap; i += 2) {
        if (i + 1 < ntap) LOADA(a1r, kp0 + i + 1);    // A issue-early
        TAP(a0r, kp0 + i);
        if (i + 2 < ntap) LOADA(a0r, kp0 + i + 2);
        if (i + 1 < ntap) TAP(a1r, kp0 + i + 1);
    }

    // ---- merge quad1 partials into quad0 via LDS (xs dead now)
    __syncthreads();
    float* msm = (float*)pool;            // 64KB: plane (n*16+r) x 256 f32
    #pragma unroll
    for (int m = 0; m < 2; ++m) {
        if (quad == 1) {
            #pragma unroll
            for (int n = 0; n < 4; ++n)
                #pragma unroll
                for (int r = 0; r < 16; ++r)
                    msm[(n * 16 + r) * 256 + ww * 64 + lane] = acc[m][n][r];
        }
        __syncthreads();
        if (quad == 0) {
            #pragma unroll
            for (int n = 0; n < 4; ++n)
                #pragma unroll
                for (int r = 0; r < 16; ++r)
                    acc[m][n][r] += msm[(n * 16 + r) * 256 + ww * 64 + lane];
        }
        __syncthreads();
    }

    // ---- epilogue (quad0): D col = l31 -> t, row = (r&3)+8*(r>>2)+4*kg -> o
    if (quad == 0) {
        const int ybase = (bb * COUT) * T_LEN;
        #pragma unroll
        for (int m = 0; m < 2; ++m) {
            #pragma unroll
            for (int n = 0; n < 4; ++n) {
                const int t = t0 + twbase + n * 32 + l31;
                #pragma unroll
                for (int r = 0; r < 16; ++r) {
                    const int o = m * 32 + (r & 3) + 8 * (r >> 2) + 4 * kg;
                    y[ybase + o * T_LEN + t] = acc[m][n][r];
                }
            }
        }
    }
}

extern "C" void kernel_launch(void* const* d_in, const int* in_sizes, int n_in,
                              void* d_out, int out_size, void* d_ws, size_t ws_size,
                              hipStream_t stream) {
    const float* x = (const float*)d_in[0];
    const float* W = (const float*)d_in[1];
    float* yout = (float*)d_out;
    unsigned short* Wt = (unsigned short*)d_ws;   // 127*4096*2 B ~= 1 MB

    wt_transform<<<(KTAPS * 512) / 256, 256, 0, stream>>>(W, Wt);

    const int grid = 8 * (T_LEN / TN);            // 256 blocks, 1/CU
    conv_mfma<<<grid, 512, 0, stream>>>(x, Wt, yout);
}

// Round 10
// 114.468 us; speedup vs baseline: 44.9936x; 1.0326x over previous
//
#include <hip/hip_runtime.h>

#define T_LEN 16384
#define CIN   64
#define COUT  64
#define KTAPS 127
#define TN    512          // t-tile per block
#define XROWS 640          // staged x rows
#define XPITCH_B 144       // row pitch in bytes (128 data + 16 pad)
#define WT_KS 4096         // COUT*CIN halfwords per tap slice

typedef __attribute__((ext_vector_type(8)))  __bf16 bf16x8;
typedef __attribute__((ext_vector_type(16))) float  f32x16;
typedef __attribute__((ext_vector_type(4)))  float  float4v;

__device__ inline unsigned short f2bf(float f) {
    unsigned u = __builtin_bit_cast(unsigned, f);
    u += 0x7fffu + ((u >> 16) & 1u);        // round-to-nearest-even
    return (unsigned short)(u >> 16);
}

// Wt[kp] slice (8KB) in MFMA-fragment order: each lane's A-fragment is one
// contiguous 16B chunk. Chunk c (0..511) of slice kp holds, for
// f=c>>6 (=cc*2+m), kg=(c>>5)&1, l31=c&31:
//   e=0..7:  bf16(W[m*32+l31][cc*16+kg*8+e][126-kp])
__global__ void wt_transform(const float* __restrict__ W,
                             unsigned short* __restrict__ Wt) {
    int t  = blockIdx.x * 256 + threadIdx.x;    // 127*512 threads
    int kp = t >> 9, c = t & 511;
    int f = c >> 6, kg = (c >> 5) & 1, l31 = c & 31;
    int cc = f >> 1, m = f & 1;
    int o = m * 32 + l31, ib = cc * 16 + kg * 8;
    const float* src = W + (o * CIN + ib) * KTAPS + (126 - kp);
    unsigned short tmp[8];
    #pragma unroll
    for (int e = 0; e < 8; ++e)
        tmp[e] = f2bf(src[e * KTAPS]);
    uint4 pk;
    pk.x = (unsigned)tmp[0] | ((unsigned)tmp[1] << 16);
    pk.y = (unsigned)tmp[2] | ((unsigned)tmp[3] << 16);
    pk.z = (unsigned)tmp[4] | ((unsigned)tmp[5] << 16);
    pk.w = (unsigned)tmp[6] | ((unsigned)tmp[7] << 16);
    *(uint4*)(Wt + kp * WT_KS + c * 8) = pk;
}

__global__ __launch_bounds__(512, 2)
void conv_mfma(const float* __restrict__ x,
               const unsigned short* __restrict__ Wt,
               float* __restrict__ y) {
    // pool: xs [0, 640*144=92160)  (merge scratch reuses [0,64K) at the end)
    __shared__ __align__(16) char pool[XROWS * XPITCH_B];
    unsigned short* xs = (unsigned short*)pool;   // [XROWS][72], 72hw=144B pitch

    const int tid = threadIdx.x;
    const int bb  = blockIdx.x >> 5;      // batch
    const int tt  = blockIdx.x & 31;      // t-tile
    const int t0  = tt * TN;

    // ---- stage x window [t0-64, t0+576) transposed into padded rows:
    //      row w, cin c at halfword w*72 + c  (pad breaks pow2 stride -> the
    //      per-lane 16B B-fragment read is bank-uniform, 8 words/bank floor)
    {
        const int cin = tid >> 3;             // 0..63
        const int s   = tid & 7;
        const float* xrow = x + (bb * CIN + cin) * T_LEN;
        for (int j = 0; j < 20; ++j) {
            const int w = 32 * j + 4 * s;
            const int u = t0 - 64 + w;        // global t (16B aligned)
            float4v v;
            if (u >= 0 && u + 4 <= T_LEN) {
                v = *(const float4v*)(xrow + u);
            } else {
                v.x = (u + 0 >= 0 && u + 0 < T_LEN) ? xrow[u + 0] : 0.f;
                v.y = (u + 1 >= 0 && u + 1 < T_LEN) ? xrow[u + 1] : 0.f;
                v.z = (u + 2 >= 0 && u + 2 < T_LEN) ? xrow[u + 2] : 0.f;
                v.w = (u + 3 >= 0 && u + 3 < T_LEN) ? xrow[u + 3] : 0.f;
            }
            #pragma unroll
            for (int e = 0; e < 4; ++e) {
                const int we = w + e;
                const float fv = (e == 0) ? v.x : (e == 1) ? v.y : (e == 2) ? v.z : v.w;
                xs[we * 72 + cin] = f2bf(fv);
            }
        }
    }

    const int lane   = tid & 63;
    const int wv     = tid >> 6;          // 0..7
    const int quad   = wv >> 2;           // tap-half owner (0/1)
    const int ww     = wv & 3;            // wave-in-quad: t-range
    const int l31    = lane & 31;
    const int kg     = lane >> 5;
    const int twbase = ww * 128;          // wave's 128-t range
    const int brow0  = twbase + l31 + 1;  // xs row at k'=0

    const int kp0  = quad ? 64 : 0;
    const int ntap = quad ? 63 : 64;

    // per-lane A-fragment global base: + kp*8192 + f*1024, f = cc*2+m
    const char* ab = (const char*)Wt + lane * 16;

    f32x16 acc[2][4] = {};                // [m: o-tile][n: t-tile]
    uint4 a0r[8], a1r[8];                 // ping-pong A prefetch (cross-tap)
    uint4 bA[4], bB[4];                   // B reg double-buffer (cross-cc)

    #define LOADA(dst, kp)                                                  \
        do { const char* p_ = ab + (kp) * 8192;                             \
            _Pragma("unroll")                                               \
            for (int f = 0; f < 8; ++f)                                     \
                dst[f] = *(const uint4*)(p_ + f * 1024); } while (0)

    // one ds_read_b128 per n: lane's B fragment is contiguous 16B
    #define LOADB(dst, rb, cidx)                                            \
        do { const char* xp_ = (const char*)xs + (rb) * XPITCH_B            \
                               + ((2 * (cidx) + kg) << 4);                  \
            _Pragma("unroll")                                               \
            for (int n = 0; n < 4; ++n)                                     \
                dst[n] = *(const uint4*)(xp_ + n * (32 * XPITCH_B));        \
        } while (0)

    #define MFMAB(bv, ar, cidx)                                             \
        do { bf16x8 a0 = __builtin_bit_cast(bf16x8, ar[(cidx) * 2 + 0]);    \
            bf16x8 a1 = __builtin_bit_cast(bf16x8, ar[(cidx) * 2 + 1]);     \
            _Pragma("unroll")                                               \
            for (int n = 0; n < 4; ++n) {                                   \
                bf16x8 b = __builtin_bit_cast(bf16x8, bv[n]);               \
                acc[0][n] = __builtin_amdgcn_mfma_f32_32x32x16_bf16(a0, b, acc[0][n], 0, 0, 0); \
                acc[1][n] = __builtin_amdgcn_mfma_f32_32x32x16_bf16(a1, b, acc[1][n], 0, 0, 0); \
            } } while (0)

    // one tap, B-pipelined; do-while(0) so `if (...) TAP(...)` guards all.
    #define TAP(ar, kp)                                                     \
        do {                                                                \
            LOADB(bB, brow0 + (kp), 1);     MFMAB(bA, ar, 0);               \
            LOADB(bA, brow0 + (kp), 2);     MFMAB(bB, ar, 1);               \
            LOADB(bB, brow0 + (kp), 3);     MFMAB(bA, ar, 2);               \
            LOADB(bA, brow0 + (kp) + 1, 0); MFMAB(bB, ar, 3);               \
        } while (0)

    LOADA(a0r, kp0);                       // overlaps the barrier
    __syncthreads();                       // xs ready (only barrier pre-merge)

    // ---- anti-phase stagger: co-resident waves on one SIMD start ~1 phase
    //      (~300 cyc) apart so one wave's MFMA cluster covers the other's
    //      LDS cluster. Keyed on both plausible wave->SIMD mappings.
    {
        const int stag = (wv & 1) + (((wv >> 2) & 1) << 1);   // 0..3
        for (int z = 0; z < stag; ++z)
            __builtin_amdgcn_s_sleep(2);                      // ~128 cyc each
    }

    LOADB(bA, brow0 + kp0, 0);             // prime B pipeline

    // barrier-free main loop: waves drift freely over their tap ranges
    for (int i = 0; i < ntap; i += 2) {
        if (i + 1 < ntap) LOADA(a1r, kp0 + i + 1);    // A issue-early
        TAP(a0r, kp0 + i);
        if (i + 2 < ntap) LOADA(a0r, kp0 + i + 2);
        if (i + 1 < ntap) TAP(a1r, kp0 + i + 1);
    }

    // ---- merge quad1 partials into quad0 via LDS (xs dead now)
    __syncthreads();
    float* msm = (float*)pool;            // 64KB: plane (n*16+r) x 256 f32
    #pragma unroll
    for (int m = 0; m < 2; ++m) {
        if (quad == 1) {
            #pragma unroll
            for (int n = 0; n < 4; ++n)
                #pragma unroll
                for (int r = 0; r < 16; ++r)
                    msm[(n * 16 + r) * 256 + ww * 64 + lane] = acc[m][n][r];
        }
        __syncthreads();
        if (quad == 0) {
            #pragma unroll
            for (int n = 0; n < 4; ++n)
                #pragma unroll
                for (int r = 0; r < 16; ++r)
                    acc[m][n][r] += msm[(n * 16 + r) * 256 + ww * 64 + lane];
        }
        __syncthreads();
    }

    // ---- epilogue (quad0): D col = l31 -> t, row = (r&3)+8*(r>>2)+4*kg -> o
    if (quad == 0) {
        const int ybase = (bb * COUT) * T_LEN;
        #pragma unroll
        for (int m = 0; m < 2; ++m) {
            #pragma unroll
            for (int n = 0; n < 4; ++n) {
                const int t = t0 + twbase + n * 32 + l31;
                #pragma unroll
                for (int r = 0; r < 16; ++r) {
                    const int o = m * 32 + (r & 3) + 8 * (r >> 2) + 4 * kg;
                    y[ybase + o * T_LEN + t] = acc[m][n][r];
                }
            }
        }
    }
}

extern "C" void kernel_launch(void* const* d_in, const int* in_sizes, int n_in,
                              void* d_out, int out_size, void* d_ws, size_t ws_size,
                              hipStream_t stream) {
    const float* x = (const float*)d_in[0];
    const float* W = (const float*)d_in[1];
    float* yout = (float*)d_out;
    unsigned short* Wt = (unsigned short*)d_ws;   // 127*4096*2 B ~= 1 MB

    wt_transform<<<(KTAPS * 512) / 256, 256, 0, stream>>>(W, Wt);

    const int grid = 8 * (T_LEN / TN);            // 256 blocks, 1/CU
    conv_mfma<<<grid, 512, 0, stream>>>(x, Wt, yout);
}